// Round 6
// baseline (1404.868 us; speedup 1.0000x reference)
//
#include <hip/hip_runtime.h>

typedef __bf16 bf16x8 __attribute__((ext_vector_type(8)));
typedef float f32x4 __attribute__((ext_vector_type(4)));

#define LDSPAD 72   // 64 + 8 bf16 pad: 144B row stride -> 2 lanes/bank on ds_read_b128 (free)

// LDS-only barrier: does NOT drain vmcnt, so global prefetch loads / fire-and-forget
// stores stay in flight across the barrier (CK block_sync_lds pattern).
__device__ __forceinline__ void sync_lds() {
    asm volatile("s_waitcnt lgkmcnt(0)" ::: "memory");
    __builtin_amdgcn_s_barrier();
}

// ---------------- DFT basis build: BT[n][j], n<2050: k=n>>1, cos/sin(2*pi*k*(544+j)/2048) ----------------
__global__ __launch_bounds__(256) void build_bdft(__bf16* __restrict__ BT)
{
    int id = blockIdx.x * 256 + threadIdx.x;
    if (id >= 2176 * 960) return;
    int n = id / 960;
    int j = id - n * 960;
    float v = 0.f;
    if (n < 2050) {
        int k = n >> 1;
        int p = (k * (544 + j)) & 2047;                // exact integer phase reduction
        float ang = (float)p * 0.0030679615757712823f; // 2*pi/2048
        v = (n & 1) ? sinf(ang) : cosf(ang);           // sign of sin irrelevant (squared)
    }
    BT[id] = (__bf16)v;
}

// ---------------- windowed frames: A[frame][j] = xp[t*240+544+j] * hann960[j], bf16 ----------------
__global__ __launch_bounds__(256) void build_frames(const float* __restrict__ x, __bf16* __restrict__ A)
{
    int id = blockIdx.x * 256 + threadIdx.x;           // one thread per 2 cols
    if (id >= 16128 * 480) return;
    int frame = id / 480;
    int jp = (id - frame * 480) * 2;
    float v[2] = {0.f, 0.f};
    if (frame < 16016) {
        int b = frame / 1001;
        int t = frame - b * 1001;
        const float* xb = x + (size_t)b * 240000;
        #pragma unroll
        for (int e = 0; e < 2; ++e) {
            int j = jp + e;
            int s = t * 240 + j - 480;                 // xp index minus pad
            if (s < 0) s = -s;                         // left reflect
            else if (s >= 240000) s = 479998 - s;      // right reflect (2L-2-s)
            float win = 0.5f - 0.5f * cosf((float)j * 0.006544984694978735f); // 2*pi/960
            v[e] = xb[s] * win;
        }
    }
    union { unsigned int u; __bf16 h[2]; } pk;
    pk.h[0] = (__bf16)v[0]; pk.h[1] = (__bf16)v[1];
    *reinterpret_cast<unsigned int*>(&A[(size_t)frame * 960 + jp]) = pk.u;
}

// ---------------- bf16 MFMA GEMM, C = A(M x Ka) * BT(N x Ka)^T.  mode 0: DFT (store bf16 C)
// mode 1: input projection (scatter fp32 into [t][dir][batch][cell][gate] `pre` with bias) ----------------
__global__ __launch_bounds__(256) void gemm_kernel(
    const __bf16* __restrict__ A, const __bf16* __restrict__ BT,
    int Ka, int kIters, int mode,
    __bf16* __restrict__ Cdft, float* __restrict__ pre,
    const float* __restrict__ b_f, const float* __restrict__ b_b)
{
    __shared__ __bf16 As[128 * LDSPAD];
    __shared__ __bf16 Bs[128 * LDSPAD];
    const int tid = threadIdx.x;
    const int wave = tid >> 6, lane = tid & 63, l15 = lane & 15, quad = lane >> 4;
    const int bn = blockIdx.x, bm = blockIdx.y;
    const int qm = wave >> 1, qn = wave & 1;
    f32x4 acc[4][4] = {};
    const int rowS = tid >> 3;          // 0..31
    const int colS = (tid & 7) * 8;     // 0..56
    const __bf16* Ag = A + (size_t)(bm * 128) * Ka;
    const __bf16* Bg = BT + (size_t)(bn * 128) * Ka;

    for (int kb = 0; kb < kIters; ++kb) {
        int k0 = kb * 64;
        #pragma unroll
        for (int p = 0; p < 4; ++p) {
            int row = p * 32 + rowS;
            *reinterpret_cast<uint4*>(&As[row * LDSPAD + colS]) =
                *reinterpret_cast<const uint4*>(&Ag[(size_t)row * Ka + k0 + colS]);
            *reinterpret_cast<uint4*>(&Bs[row * LDSPAD + colS]) =
                *reinterpret_cast<const uint4*>(&Bg[(size_t)row * Ka + k0 + colS]);
        }
        __syncthreads();
        #pragma unroll
        for (int ks = 0; ks < 2; ++ks) {
            bf16x8 af[4], bfr[4];
            #pragma unroll
            for (int i = 0; i < 4; ++i)
                af[i] = *reinterpret_cast<const bf16x8*>(&As[(qm * 64 + i * 16 + l15) * LDSPAD + ks * 32 + quad * 8]);
            #pragma unroll
            for (int j = 0; j < 4; ++j)
                bfr[j] = *reinterpret_cast<const bf16x8*>(&Bs[(qn * 64 + j * 16 + l15) * LDSPAD + ks * 32 + quad * 8]);
            #pragma unroll
            for (int i = 0; i < 4; ++i)
                #pragma unroll
                for (int j = 0; j < 4; ++j)
                    acc[i][j] = __builtin_amdgcn_mfma_f32_16x16x32_bf16(af[i], bfr[j], acc[i][j], 0, 0, 0);
        }
        __syncthreads();
    }

    if (mode == 0) {
        #pragma unroll
        for (int i = 0; i < 4; ++i)
            #pragma unroll
            for (int j = 0; j < 4; ++j) {
                int n = bn * 128 + qn * 64 + j * 16 + l15;
                #pragma unroll
                for (int r = 0; r < 4; ++r) {
                    int m = bm * 128 + qm * 64 + i * 16 + quad * 4 + r;
                    Cdft[(size_t)m * 2176 + n] = (__bf16)acc[i][j][r];
                }
            }
    } else {
        for (int i = 0; i < 4; ++i)
            for (int j = 0; j < 4; ++j) {
                int n = bn * 128 + qn * 64 + j * 16 + l15;   // n < 1024
                float bias = (n < 512) ? b_f[n] : b_b[n - 512];
                int dirg = n >> 9;
                int ngate = n & 511;
                int g = ngate >> 7;          // gate index: 0=i 1=f 2=g 3=o
                int jj = ngate & 127;        // hidden unit
                for (int r = 0; r < 4; ++r) {
                    int m = bm * 128 + qm * 64 + i * 16 + quad * 4 + r;
                    if (m < 16016) {
                        int b = m / 1001;
                        int t = m - b * 1001;
                        // pre[t][dirg][batch b][cell jj][gate g]
                        size_t off = ((size_t)(t * 2 + dirg) * 16 + b) * 512 + jj * 4 + g;
                        pre[off] = acc[i][j][r] + bias;
                    }
                }
            }
    }
}

// ---------------- feature build: gather harmonic energies from bf16 DFT output ----------------
__global__ __launch_bounds__(320) void build_feat(const float* __restrict__ f0,
    const __bf16* __restrict__ Cdft, __bf16* __restrict__ feat)
{
    int frame = blockIdx.x;
    int d = threadIdx.x;   // 0..319
    float val = 0.f;
    if (frame < 16016) {
        int b = frame / 1001;
        int t = frame - b * 1001;
        float f0v = f0[b * 1001 + t];
        float f0nz = (f0v > 0.f) ? f0v : 80.f;   // SR/NUM_BANDS*0.5
        if (d < 300) {
            float mult = (d == 0) ? 0.5f : (float)(d + 1) * 0.5f;
            float harm = f0nz * mult;
            int kidx = (int)rintf(harm * (1.0f / 11.71875f));  // FREQ_INTERVAL = 24000/2048
            kidx = min(max(kidx, 0), 1024);
            float e = 0.f;
            if (kidx < 1024) {   // bin 1024 forced to zero by reference
                unsigned int pk = *reinterpret_cast<const unsigned int*>(&Cdft[(size_t)frame * 2176 + 2 * kidx]);
                union { unsigned int u; __bf16 h[2]; } c; c.u = pk;
                float c0 = (float)c.h[0], c1 = (float)c.h[1];
                e = c0 * c0 + c1 * c1;
            }
            val = (logf(e + 1e-8f) + 18.f) * (1.f / 23.f);
        } else if (d == 300) {
            val = logf(f0nz);
        }
    }
    feat[(size_t)frame * 320 + d] = (__bf16)val;
}

// ---------------- stacked input-projection weights, transposed + K-padded, bf16 ----------------
__global__ __launch_bounds__(256) void build_wt(const float* __restrict__ w_ih_f,
    const float* __restrict__ w_ih_b, __bf16* __restrict__ WT)
{
    int id = blockIdx.x * 256 + threadIdx.x;
    if (id >= 1024 * 320) return;
    int n = id / 320;
    int k = id - n * 320;
    float v = 0.f;
    if (k < 301) v = (n < 512) ? w_ih_f[n * 301 + k] : w_ih_b[(n - 512) * 301 + k];
    WT[id] = (__bf16)v;
}

// ---------------- batched BiLSTM: 4 blocks = dir(2) x batch-half(2), 8 batches each.
// Z[512][8] = W_hh(512x128, perm rows s=4j+g) . H[128][8] with batches as REAL MFMA
// B-columns (no broadcast waste, no cndmask selects). W in A-register-fragments.
// acc[mt][r] = gate r of cell j=wave*16+mt*4+quad, batch l15; acc INITIALIZED with pre
// (C-operand). H in LDS [batch][cell] bf16 with +8 pad (uniform bank distribution);
// cols 8..15 read permanently-zero rows (benign). ONE lgkm-only barrier/step; pre
// prefetched 2 steps via unroll-2 + two register sets (no end-of-step vmcnt(0));
// h_out stores fire-and-forget. ----------------
__global__ __launch_bounds__(512, 2) void lstm_kernel(
    const float* __restrict__ w_hh_f, const float* __restrict__ w_hh_b,
    const float* __restrict__ pre, float* __restrict__ h_out)
{
    const int bid = blockIdx.x;          // 0..3
    const int dir = bid >> 1;
    const int bh  = bid & 1;             // batches bh*8 .. bh*8+7
    const float* w_hh = dir ? w_hh_b : w_hh_f;
    const int tid = threadIdx.x;
    const int wave = tid >> 6, lane = tid & 63, l15 = lane & 15, quad = lane >> 4;
    const int bloc = l15 & 7;            // local batch (lanes l15>=8 duplicate, never write)
    const bool wr = (l15 < 8);

    __shared__ __bf16 H[2][16][136];     // [buf][batch col][cell], pad 8 -> 272B row stride

    for (int i = tid; i < 2 * 16 * 136; i += 512) (&H[0][0][0])[i] = (__bf16)0.f;

    // A-fragments: m-tile mt, row-in-tile m=l15 -> perm row s = wave*64 + mt*16 + l15;
    // W_hh row = (s&3)*128 + (s>>2); k = kt*32 + quad*8 + e
    bf16x8 afrag[4][4];
    #pragma unroll
    for (int mt = 0; mt < 4; ++mt) {
        int s = wave * 64 + mt * 16 + l15;
        const float* wrow = w_hh + (size_t)((s & 3) * 128 + (s >> 2)) * 128;
        #pragma unroll
        for (int kt = 0; kt < 4; ++kt) {
            bf16x8 v;
            #pragma unroll
            for (int e = 0; e < 8; ++e) v[e] = (__bf16)wrow[kt * 32 + quad * 8 + e];
            afrag[mt][kt] = v;
        }
    }

    const int t0 = dir ? 1000 : 0;
    const ptrdiff_t pre_sstride  = dir ? -16384 : 16384;   // floats per step
    const ptrdiff_t hout_sstride = dir ? -2048  : 2048;    // floats per step
    // pre[t][dir][batch][cell][gate]; this lane: batch bh*8+bloc, cells wave*16+mt*4+quad
    const float* pre_base = pre + ((size_t)(t0 * 2 + dir) * 16 + bh * 8 + bloc) * 512
                                + (size_t)(wave * 16 + quad) * 4;
    float* hout_base = h_out + ((size_t)dir * 1001 + t0) * 2048
                             + (size_t)(bh * 8 + bloc) * 128 + wave * 16 + quad;

    auto load_pre = [&](f32x4* dst, int sidx) {
        const float* p = pre_base + (ptrdiff_t)sidx * pre_sstride;
        #pragma unroll
        for (int mt = 0; mt < 4; ++mt)
            dst[mt] = *reinterpret_cast<const f32x4*>(p + mt * 16);
    };

    float cstate[4] = {0.f, 0.f, 0.f, 0.f};
    const float L2E = 1.4426950408889634f;

    auto body = [&](int s, f32x4* P) {
        const __bf16* Hr = &H[s & 1][0][0];
        bf16x8 bfr[4];
        #pragma unroll
        for (int kt = 0; kt < 4; ++kt)
            bfr[kt] = *reinterpret_cast<const bf16x8*>(&Hr[l15 * 136 + kt * 32 + quad * 8]);

        f32x4 acc[4];
        #pragma unroll
        for (int mt = 0; mt < 4; ++mt) {
            acc[mt] = P[mt];   // C-operand init = pre (valid for this lane's column)
            #pragma unroll
            for (int kt = 0; kt < 4; ++kt)
                acc[mt] = __builtin_amdgcn_mfma_f32_16x16x32_bf16(afrag[mt][kt], bfr[kt], acc[mt], 0, 0, 0);
        }

        __bf16* Hw = &H[(s + 1) & 1][0][0];
        float* hp = hout_base + (ptrdiff_t)s * hout_sstride;
        #pragma unroll
        for (int mt = 0; mt < 4; ++mt) {
            float zi = acc[mt][0], zf = acc[mt][1], zg = acc[mt][2], zo = acc[mt][3];
            // fused gates: 5 exp2 + 3 rcp, exact algebra
            float A = __builtin_amdgcn_exp2f(-L2E * zi);
            float B = __builtin_amdgcn_exp2f(-L2E * zf);
            float C = __builtin_amdgcn_exp2f(-2.f * L2E * zg);
            float D = __builtin_amdgcn_exp2f(-L2E * zo);
            float Pp = (1.f + A) * (1.f + C);
            float Q = 1.f + B;
            float cn = (cstate[mt] * Pp + (1.f - C) * Q) * __builtin_amdgcn_rcpf(Pp * Q);
            cstate[mt] = cn;
            float E = __builtin_amdgcn_exp2f(-2.f * L2E * cn);
            float h = (1.f - E) * __builtin_amdgcn_rcpf((1.f + D) * (1.f + E));
            int j = wave * 16 + mt * 4 + quad;
            if (wr) {
                Hw[bloc * 136 + j] = (__bf16)h;
                hp[mt * 4] = h;              // fire-and-forget (cell stride 4 within row)
            }
        }
    };

    f32x4 PA[4], PB[4];
    load_pre(PA, 0);
    load_pre(PB, 1);
    __syncthreads();   // H zero-init visible

    for (int s = 0; s < 1001; s += 2) {
        body(s, PA);
        load_pre(PA, s + 2);   // overrun reads land in adjacent ws buffers: safe, unused
        sync_lds();
        if (s + 1 < 1001) {
            body(s + 1, PB);
            load_pre(PB, s + 3);
            sync_lds();
        }
    }
}

// ---------------- LayerNorm(concat(hf,hb)) + out projection; one wave per (b,t) row ----------------
__global__ __launch_bounds__(256) void out_kernel(
    const float* __restrict__ h_out, const float* __restrict__ ln_g, const float* __restrict__ ln_b,
    const float* __restrict__ out_w, const float* __restrict__ out_b, float* __restrict__ out)
{
    __shared__ __bf16 w_lds[256 * 66];   // [k][o], padded: conflict-free both directions
    __shared__ float hn_lds[4 * 256];
    const int tid = threadIdx.x;
    const int wave = tid >> 6, lane = tid & 63;
    for (int idx = tid; idx < 16384; idx += 256) {
        int o = idx >> 8, k = idx & 255;
        w_lds[k * 66 + o] = (__bf16)out_w[o * 256 + k];
    }
    int r = blockIdx.x * 4 + wave;       // < 16016
    int b = r / 1001, t = r - b * 1001;
    size_t basef = (((size_t)0 * 1001 + t) * 16 + b) * 128;
    size_t baseb = (((size_t)1 * 1001 + t) * 16 + b) * 128;
    float h0 = h_out[basef + lane];
    float h1 = h_out[basef + 64 + lane];
    float h2 = h_out[baseb + lane];
    float h3 = h_out[baseb + 64 + lane];
    float s1 = h0 + h1 + h2 + h3;
    float s2 = h0 * h0 + h1 * h1 + h2 * h2 + h3 * h3;
    #pragma unroll
    for (int m = 32; m >= 1; m >>= 1) {
        s1 += __shfl_xor(s1, m, 64);
        s2 += __shfl_xor(s2, m, 64);
    }
    float mu = s1 * (1.f / 256.f);
    float var = s2 * (1.f / 256.f) - mu * mu;   // biased var, matches jnp var
    float rstd = rsqrtf(var + 1e-5f);
    int k0 = lane, k1 = 64 + lane, k2 = 128 + lane, k3 = 192 + lane;
    hn_lds[wave * 256 + k0] = (h0 - mu) * rstd * ln_g[k0] + ln_b[k0];
    hn_lds[wave * 256 + k1] = (h1 - mu) * rstd * ln_g[k1] + ln_b[k1];
    hn_lds[wave * 256 + k2] = (h2 - mu) * rstd * ln_g[k2] + ln_b[k2];
    hn_lds[wave * 256 + k3] = (h3 - mu) * rstd * ln_g[k3] + ln_b[k3];
    __syncthreads();
    const float* hn = &hn_lds[wave * 256];
    float acc = 0.f;
    #pragma unroll 4
    for (int k = 0; k < 256; ++k)
        acc += hn[k] * (float)w_lds[k * 66 + lane];   // hn[k]: LDS broadcast
    out[(size_t)r * 64 + lane] = acc + out_b[lane];
}

extern "C" void kernel_launch(void* const* d_in, const int* in_sizes, int n_in,
                              void* d_out, int out_size, void* d_ws, size_t ws_size,
                              hipStream_t stream) {
    const float* x      = (const float*)d_in[0];
    const float* f0     = (const float*)d_in[1];
    const float* w_ih_f = (const float*)d_in[2];
    const float* w_hh_f = (const float*)d_in[3];
    const float* b_f    = (const float*)d_in[4];
    const float* w_ih_b = (const float*)d_in[5];
    const float* w_hh_b = (const float*)d_in[6];
    const float* b_b    = (const float*)d_in[7];
    const float* ln_g   = (const float*)d_in[8];
    const float* ln_b   = (const float*)d_in[9];
    const float* out_w  = (const float*)d_in[10];
    const float* out_b  = (const float*)d_in[11];
    float* out = (float*)d_out;

    char* ws = (char*)d_ws;
    size_t off = 0;
    auto alloc = [&](size_t bytes) { size_t o = off; off = (off + bytes + 255) & ~(size_t)255; return o; };
    __bf16* A     = (__bf16*)(ws + alloc((size_t)16128 * 960 * 2));
    __bf16* BT    = (__bf16*)(ws + alloc((size_t)2176 * 960 * 2));
    __bf16* Cdft  = (__bf16*)(ws + alloc((size_t)16128 * 2176 * 2));
    __bf16* feat  = (__bf16*)(ws + alloc((size_t)16128 * 320 * 2));
    __bf16* WT    = (__bf16*)(ws + alloc((size_t)1024 * 320 * 2));
    float*  pre   = (float*)(ws + alloc((size_t)1001 * 2 * 16 * 512 * 4));
    float*  h_out = (float*)(ws + alloc((size_t)2 * 1001 * 16 * 128 * 4));
    (void)ws_size; (void)in_sizes; (void)n_in; (void)out_size;

    build_bdft  <<<(2176 * 960 + 255) / 256, 256, 0, stream>>>(BT);
    build_frames<<<(16128 * 480 + 255) / 256, 256, 0, stream>>>(x, A);
    gemm_kernel <<<dim3(17, 126), 256, 0, stream>>>(A, BT, 960, 15, 0, Cdft, nullptr, nullptr, nullptr);
    build_feat  <<<16128, 320, 0, stream>>>(f0, Cdft, feat);
    build_wt    <<<(1024 * 320 + 255) / 256, 256, 0, stream>>>(w_ih_f, w_ih_b, WT);
    gemm_kernel <<<dim3(8, 126), 256, 0, stream>>>(feat, WT, 320, 5, 1, nullptr, pre, b_f, b_b);
    lstm_kernel <<<4, 512, 0, stream>>>(w_hh_f, w_hh_b, pre, h_out);
    out_kernel  <<<4004, 256, 0, stream>>>(h_out, ln_g, ln_b, out_w, out_b, out);
}

// Round 7
// 769.025 us; speedup vs baseline: 1.8268x; 1.8268x over previous
//
#include <hip/hip_runtime.h>

typedef __bf16 bf16x8 __attribute__((ext_vector_type(8)));
typedef float f32x4 __attribute__((ext_vector_type(4)));

#define LDSPAD 72   // 64 + 8 bf16 pad: 144B row stride -> 2 lanes/bank on ds_read_b128 (free)

// LDS-only barrier: does NOT drain vmcnt, so global prefetch loads / fire-and-forget
// stores stay in flight across the barrier (CK block_sync_lds pattern).
__device__ __forceinline__ void sync_lds() {
    asm volatile("s_waitcnt lgkmcnt(0)" ::: "memory");
    __builtin_amdgcn_s_barrier();
}

// ---------------- DFT basis build: BT[n][j], n<2050: k=n>>1, cos/sin(2*pi*k*(544+j)/2048) ----------------
__global__ __launch_bounds__(256) void build_bdft(__bf16* __restrict__ BT)
{
    int id = blockIdx.x * 256 + threadIdx.x;
    if (id >= 2176 * 960) return;
    int n = id / 960;
    int j = id - n * 960;
    float v = 0.f;
    if (n < 2050) {
        int k = n >> 1;
        int p = (k * (544 + j)) & 2047;                // exact integer phase reduction
        float ang = (float)p * 0.0030679615757712823f; // 2*pi/2048
        v = (n & 1) ? sinf(ang) : cosf(ang);           // sign of sin irrelevant (squared)
    }
    BT[id] = (__bf16)v;
}

// ---------------- windowed frames: A[frame][j] = xp[t*240+544+j] * hann960[j], bf16 ----------------
__global__ __launch_bounds__(256) void build_frames(const float* __restrict__ x, __bf16* __restrict__ A)
{
    int id = blockIdx.x * 256 + threadIdx.x;           // one thread per 2 cols
    if (id >= 16128 * 480) return;
    int frame = id / 480;
    int jp = (id - frame * 480) * 2;
    float v[2] = {0.f, 0.f};
    if (frame < 16016) {
        int b = frame / 1001;
        int t = frame - b * 1001;
        const float* xb = x + (size_t)b * 240000;
        #pragma unroll
        for (int e = 0; e < 2; ++e) {
            int j = jp + e;
            int s = t * 240 + j - 480;                 // xp index minus pad
            if (s < 0) s = -s;                         // left reflect
            else if (s >= 240000) s = 479998 - s;      // right reflect (2L-2-s)
            float win = 0.5f - 0.5f * cosf((float)j * 0.006544984694978735f); // 2*pi/960
            v[e] = xb[s] * win;
        }
    }
    union { unsigned int u; __bf16 h[2]; } pk;
    pk.h[0] = (__bf16)v[0]; pk.h[1] = (__bf16)v[1];
    *reinterpret_cast<unsigned int*>(&A[(size_t)frame * 960 + jp]) = pk.u;
}

// ---------------- bf16 MFMA GEMM, C = A(M x Ka) * BT(N x Ka)^T.  mode 0: DFT (store bf16 C)
// mode 1: input projection (scatter fp32 into [t][dir][batch][cell][gate] `pre` with bias) ----------------
__global__ __launch_bounds__(256) void gemm_kernel(
    const __bf16* __restrict__ A, const __bf16* __restrict__ BT,
    int Ka, int kIters, int mode,
    __bf16* __restrict__ Cdft, float* __restrict__ pre,
    const float* __restrict__ b_f, const float* __restrict__ b_b)
{
    __shared__ __bf16 As[128 * LDSPAD];
    __shared__ __bf16 Bs[128 * LDSPAD];
    const int tid = threadIdx.x;
    const int wave = tid >> 6, lane = tid & 63, l15 = lane & 15, quad = lane >> 4;
    const int bn = blockIdx.x, bm = blockIdx.y;
    const int qm = wave >> 1, qn = wave & 1;
    f32x4 acc[4][4] = {};
    const int rowS = tid >> 3;          // 0..31
    const int colS = (tid & 7) * 8;     // 0..56
    const __bf16* Ag = A + (size_t)(bm * 128) * Ka;
    const __bf16* Bg = BT + (size_t)(bn * 128) * Ka;

    for (int kb = 0; kb < kIters; ++kb) {
        int k0 = kb * 64;
        #pragma unroll
        for (int p = 0; p < 4; ++p) {
            int row = p * 32 + rowS;
            *reinterpret_cast<uint4*>(&As[row * LDSPAD + colS]) =
                *reinterpret_cast<const uint4*>(&Ag[(size_t)row * Ka + k0 + colS]);
            *reinterpret_cast<uint4*>(&Bs[row * LDSPAD + colS]) =
                *reinterpret_cast<const uint4*>(&Bg[(size_t)row * Ka + k0 + colS]);
        }
        __syncthreads();
        #pragma unroll
        for (int ks = 0; ks < 2; ++ks) {
            bf16x8 af[4], bfr[4];
            #pragma unroll
            for (int i = 0; i < 4; ++i)
                af[i] = *reinterpret_cast<const bf16x8*>(&As[(qm * 64 + i * 16 + l15) * LDSPAD + ks * 32 + quad * 8]);
            #pragma unroll
            for (int j = 0; j < 4; ++j)
                bfr[j] = *reinterpret_cast<const bf16x8*>(&Bs[(qn * 64 + j * 16 + l15) * LDSPAD + ks * 32 + quad * 8]);
            #pragma unroll
            for (int i = 0; i < 4; ++i)
                #pragma unroll
                for (int j = 0; j < 4; ++j)
                    acc[i][j] = __builtin_amdgcn_mfma_f32_16x16x32_bf16(af[i], bfr[j], acc[i][j], 0, 0, 0);
        }
        __syncthreads();
    }

    if (mode == 0) {
        #pragma unroll
        for (int i = 0; i < 4; ++i)
            #pragma unroll
            for (int j = 0; j < 4; ++j) {
                int n = bn * 128 + qn * 64 + j * 16 + l15;
                #pragma unroll
                for (int r = 0; r < 4; ++r) {
                    int m = bm * 128 + qm * 64 + i * 16 + quad * 4 + r;
                    Cdft[(size_t)m * 2176 + n] = (__bf16)acc[i][j][r];
                }
            }
    } else {
        for (int i = 0; i < 4; ++i)
            for (int j = 0; j < 4; ++j) {
                int n = bn * 128 + qn * 64 + j * 16 + l15;   // n < 1024
                float bias = (n < 512) ? b_f[n] : b_b[n - 512];
                int dirg = n >> 9;
                int ngate = n & 511;
                int g = ngate >> 7;          // gate index: 0=i 1=f 2=g 3=o
                int jj = ngate & 127;        // hidden unit
                for (int r = 0; r < 4; ++r) {
                    int m = bm * 128 + qm * 64 + i * 16 + quad * 4 + r;
                    if (m < 16016) {
                        int b = m / 1001;
                        int t = m - b * 1001;
                        // pre[t][dirg][batch b][cell jj][gate g]
                        size_t off = ((size_t)(t * 2 + dirg) * 16 + b) * 512 + jj * 4 + g;
                        pre[off] = acc[i][j][r] + bias;
                    }
                }
            }
    }
}

// ---------------- feature build: gather harmonic energies from bf16 DFT output ----------------
__global__ __launch_bounds__(320) void build_feat(const float* __restrict__ f0,
    const __bf16* __restrict__ Cdft, __bf16* __restrict__ feat)
{
    int frame = blockIdx.x;
    int d = threadIdx.x;   // 0..319
    float val = 0.f;
    if (frame < 16016) {
        int b = frame / 1001;
        int t = frame - b * 1001;
        float f0v = f0[b * 1001 + t];
        float f0nz = (f0v > 0.f) ? f0v : 80.f;   // SR/NUM_BANDS*0.5
        if (d < 300) {
            float mult = (d == 0) ? 0.5f : (float)(d + 1) * 0.5f;
            float harm = f0nz * mult;
            int kidx = (int)rintf(harm * (1.0f / 11.71875f));  // FREQ_INTERVAL = 24000/2048
            kidx = min(max(kidx, 0), 1024);
            float e = 0.f;
            if (kidx < 1024) {   // bin 1024 forced to zero by reference
                unsigned int pk = *reinterpret_cast<const unsigned int*>(&Cdft[(size_t)frame * 2176 + 2 * kidx]);
                union { unsigned int u; __bf16 h[2]; } c; c.u = pk;
                float c0 = (float)c.h[0], c1 = (float)c.h[1];
                e = c0 * c0 + c1 * c1;
            }
            val = (logf(e + 1e-8f) + 18.f) * (1.f / 23.f);
        } else if (d == 300) {
            val = logf(f0nz);
        }
    }
    feat[(size_t)frame * 320 + d] = (__bf16)val;
}

// ---------------- stacked input-projection weights, transposed + K-padded, bf16 ----------------
__global__ __launch_bounds__(256) void build_wt(const float* __restrict__ w_ih_f,
    const float* __restrict__ w_ih_b, __bf16* __restrict__ WT)
{
    int id = blockIdx.x * 256 + threadIdx.x;
    if (id >= 1024 * 320) return;
    int n = id / 320;
    int k = id - n * 320;
    float v = 0.f;
    if (k < 301) v = (n < 512) ? w_ih_f[n * 301 + k] : w_ih_b[(n - 512) * 301 + k];
    WT[id] = (__bf16)v;
}

// ---------------- batch-parallel BiLSTM: 32 blocks = (batch 16) x (dir 2), one CU each.
// 8 waves; wave w owns perm rows [w*64, w*64+64) of W_hh (perm s=4j+g) in A-register
// fragments -> those rows are EXACTLY cells w*16..w*16+15, all 4 gates. After the MFMAs
// (h broadcast in all 16 B-cols), lane (quad,l15) with quad==(l15&3) holds cell
// w*16+l15's full gate f32x4 in acc[l15>>2]: one 2-level cndmask select, gate chain,
// done — no redundancy, no z LDS round-trip. ONE lgkm-only barrier/step; pre ([t][dir]
// [b][cell][gate], padded +-2 steps) prefetched 2 deep via unroll-2 PA/PB register sets
// (no per-step movs, no vmcnt(0)); h_out stores fire-and-forget. ----------------
__global__ __launch_bounds__(512, 2) void lstm_kernel(
    const float* __restrict__ w_hh_f, const float* __restrict__ w_hh_b,
    const float* __restrict__ pre, float* __restrict__ h_out)
{
    const int bid = blockIdx.x;          // 0..31
    const int b   = bid & 15;
    const int dir = bid >> 4;
    const float* w_hh = dir ? w_hh_b : w_hh_f;
    const int tid = threadIdx.x;
    const int wave = tid >> 6, lane = tid & 63, l15 = lane & 15, quad = lane >> 4;
    const int msel = l15 >> 2;
    const bool own = (quad == (l15 & 3));    // this lane owns cell cellj
    const int cellj = wave * 16 + l15;

    __shared__ __bf16 h_lds[2][128];     // double-buffered h(t)

    // A-fragments: perm row s = wave*64 + mt*16 + l15; W_hh row = (s&3)*128 + (s>>2)
    bf16x8 afrag[4][4];
    #pragma unroll
    for (int mt = 0; mt < 4; ++mt) {
        int s = wave * 64 + mt * 16 + l15;
        const float* wrow = w_hh + (size_t)((s & 3) * 128 + (s >> 2)) * 128;
        #pragma unroll
        for (int kt = 0; kt < 4; ++kt) {
            bf16x8 v;
            #pragma unroll
            for (int e = 0; e < 8; ++e) v[e] = (__bf16)wrow[kt * 32 + quad * 8 + e];
            afrag[mt][kt] = v;
        }
    }

    if (tid < 128) h_lds[0][tid] = (__bf16)0.f;

    const int t0 = dir ? 1000 : 0;
    const ptrdiff_t pre_sstride  = dir ? -16384 : 16384;   // floats per step
    const ptrdiff_t hout_sstride = dir ? -2048  : 2048;    // floats per step
    // pre[t][dir][b][cell][gate]; this lane reads cell cellj's 4 gates
    const float* pre_base = pre + ((size_t)(t0 * 2 + dir) * 16 + b) * 512 + (size_t)cellj * 4;
    float* hout_base = h_out + (((size_t)dir * 1001 + t0) * 16 + b) * 128;

    float cstate = 0.f;
    const float L2E = 1.4426950408889634f;

    auto body = [&](int s, f32x4 P) {
        const __bf16* hb = h_lds[s & 1];
        bf16x8 bfr[4];
        #pragma unroll
        for (int kt = 0; kt < 4; ++kt)
            bfr[kt] = *reinterpret_cast<const bf16x8*>(&hb[kt * 32 + quad * 8]);

        f32x4 acc[4] = {};
        #pragma unroll
        for (int kt = 0; kt < 4; ++kt)
            #pragma unroll
            for (int mt = 0; mt < 4; ++mt)
                acc[mt] = __builtin_amdgcn_mfma_f32_16x16x32_bf16(afrag[mt][kt], bfr[kt], acc[mt], 0, 0, 0);

        // z4 = acc[msel] (valid on lanes with quad == (l15&3))
        f32x4 t01 = (msel & 1) ? acc[1] : acc[0];
        f32x4 t23 = (msel & 1) ? acc[3] : acc[2];
        f32x4 z4  = (msel & 2) ? t23 : t01;

        float zi = z4[0] + P[0], zf = z4[1] + P[1];
        float zg = z4[2] + P[2], zo = z4[3] + P[3];
        // fused gates: 5 exp2 + 3 rcp, exact algebra
        float A = __builtin_amdgcn_exp2f(-L2E * zi);
        float B = __builtin_amdgcn_exp2f(-L2E * zf);
        float C = __builtin_amdgcn_exp2f(-2.f * L2E * zg);
        float D = __builtin_amdgcn_exp2f(-L2E * zo);
        float Pp = (1.f + A) * (1.f + C);
        float Q = 1.f + B;
        float cn = (cstate * Pp + (1.f - C) * Q) * __builtin_amdgcn_rcpf(Pp * Q);
        if (own) cstate = cn;
        float E = __builtin_amdgcn_exp2f(-2.f * L2E * cn);
        float h = (1.f - E) * __builtin_amdgcn_rcpf((1.f + D) * (1.f + E));

        if (own) {
            h_lds[(s + 1) & 1][cellj] = (__bf16)h;
            hout_base[(ptrdiff_t)s * hout_sstride + cellj] = h;   // fire-and-forget
        }
    };

    auto load_pre = [&](int sidx) -> f32x4 {
        return *reinterpret_cast<const f32x4*>(pre_base + (ptrdiff_t)sidx * pre_sstride);
    };

    f32x4 PA = load_pre(0);
    f32x4 PB = load_pre(1);
    __syncthreads();   // h_lds[0] init visible

    for (int s = 0; s < 1001; s += 2) {
        body(s, PA);
        PA = load_pre(s + 2);   // unconditional: pre is padded +-2 steps
        sync_lds();
        if (s + 1 < 1001) {
            body(s + 1, PB);
            PB = load_pre(s + 3);
            sync_lds();
        }
    }
}

// ---------------- LayerNorm(concat(hf,hb)) + out projection; one wave per (b,t) row ----------------
__global__ __launch_bounds__(256) void out_kernel(
    const float* __restrict__ h_out, const float* __restrict__ ln_g, const float* __restrict__ ln_b,
    const float* __restrict__ out_w, const float* __restrict__ out_b, float* __restrict__ out)
{
    __shared__ __bf16 w_lds[256 * 66];   // [k][o], padded: conflict-free both directions
    __shared__ float hn_lds[4 * 256];
    const int tid = threadIdx.x;
    const int wave = tid >> 6, lane = tid & 63;
    for (int idx = tid; idx < 16384; idx += 256) {
        int o = idx >> 8, k = idx & 255;
        w_lds[k * 66 + o] = (__bf16)out_w[o * 256 + k];
    }
    int r = blockIdx.x * 4 + wave;       // < 16016
    int b = r / 1001, t = r - b * 1001;
    size_t basef = (((size_t)0 * 1001 + t) * 16 + b) * 128;
    size_t baseb = (((size_t)1 * 1001 + t) * 16 + b) * 128;
    float h0 = h_out[basef + lane];
    float h1 = h_out[basef + 64 + lane];
    float h2 = h_out[baseb + lane];
    float h3 = h_out[baseb + 64 + lane];
    float s1 = h0 + h1 + h2 + h3;
    float s2 = h0 * h0 + h1 * h1 + h2 * h2 + h3 * h3;
    #pragma unroll
    for (int m = 32; m >= 1; m >>= 1) {
        s1 += __shfl_xor(s1, m, 64);
        s2 += __shfl_xor(s2, m, 64);
    }
    float mu = s1 * (1.f / 256.f);
    float var = s2 * (1.f / 256.f) - mu * mu;   // biased var, matches jnp var
    float rstd = rsqrtf(var + 1e-5f);
    int k0 = lane, k1 = 64 + lane, k2 = 128 + lane, k3 = 192 + lane;
    hn_lds[wave * 256 + k0] = (h0 - mu) * rstd * ln_g[k0] + ln_b[k0];
    hn_lds[wave * 256 + k1] = (h1 - mu) * rstd * ln_g[k1] + ln_b[k1];
    hn_lds[wave * 256 + k2] = (h2 - mu) * rstd * ln_g[k2] + ln_b[k2];
    hn_lds[wave * 256 + k3] = (h3 - mu) * rstd * ln_g[k3] + ln_b[k3];
    __syncthreads();
    const float* hn = &hn_lds[wave * 256];
    float acc = 0.f;
    #pragma unroll 4
    for (int k = 0; k < 256; ++k)
        acc += hn[k] * (float)w_lds[k * 66 + lane];   // hn[k]: LDS broadcast
    out[(size_t)r * 64 + lane] = acc + out_b[lane];
}

extern "C" void kernel_launch(void* const* d_in, const int* in_sizes, int n_in,
                              void* d_out, int out_size, void* d_ws, size_t ws_size,
                              hipStream_t stream) {
    const float* x      = (const float*)d_in[0];
    const float* f0     = (const float*)d_in[1];
    const float* w_ih_f = (const float*)d_in[2];
    const float* w_hh_f = (const float*)d_in[3];
    const float* b_f    = (const float*)d_in[4];
    const float* w_ih_b = (const float*)d_in[5];
    const float* w_hh_b = (const float*)d_in[6];
    const float* b_b    = (const float*)d_in[7];
    const float* ln_g   = (const float*)d_in[8];
    const float* ln_b   = (const float*)d_in[9];
    const float* out_w  = (const float*)d_in[10];
    const float* out_b  = (const float*)d_in[11];
    float* out = (float*)d_out;

    char* ws = (char*)d_ws;
    size_t off = 0;
    auto alloc = [&](size_t bytes) { size_t o = off; off = (off + bytes + 255) & ~(size_t)255; return o; };
    __bf16* A     = (__bf16*)(ws + alloc((size_t)16128 * 960 * 2));
    __bf16* BT    = (__bf16*)(ws + alloc((size_t)2176 * 960 * 2));
    __bf16* Cdft  = (__bf16*)(ws + alloc((size_t)16128 * 2176 * 2));
    __bf16* feat  = (__bf16*)(ws + alloc((size_t)16128 * 320 * 2));
    __bf16* WT    = (__bf16*)(ws + alloc((size_t)1024 * 320 * 2));
    // pre padded +-2 timesteps so the LSTM prefetch needs no bounds check
    float*  preA  = (float*)(ws + alloc((size_t)(1001 * 2 + 8) * 16 * 512 * 4));
    float*  pre   = preA + (size_t)4 * 16 * 512;
    float*  h_out = (float*)(ws + alloc((size_t)2 * 1001 * 16 * 128 * 4));
    (void)ws_size; (void)in_sizes; (void)n_in; (void)out_size;

    build_bdft  <<<(2176 * 960 + 255) / 256, 256, 0, stream>>>(BT);
    build_frames<<<(16128 * 480 + 255) / 256, 256, 0, stream>>>(x, A);
    gemm_kernel <<<dim3(17, 126), 256, 0, stream>>>(A, BT, 960, 15, 0, Cdft, nullptr, nullptr, nullptr);
    build_feat  <<<16016, 320, 0, stream>>>(f0, Cdft, feat);
    build_wt    <<<(1024 * 320 + 255) / 256, 256, 0, stream>>>(w_ih_f, w_ih_b, WT);
    gemm_kernel <<<dim3(8, 126), 256, 0, stream>>>(feat, WT, 320, 5, 1, nullptr, pre, b_f, b_b);
    lstm_kernel <<<32, 512, 0, stream>>>(w_hh_f, w_hh_b, pre, h_out);
    out_kernel  <<<4004, 256, 0, stream>>>(h_out, ln_g, ln_b, out_w, out_b, out);
}

// Round 8
// 759.936 us; speedup vs baseline: 1.8487x; 1.0120x over previous
//
#include <hip/hip_runtime.h>

typedef __bf16 bf16x8 __attribute__((ext_vector_type(8)));
typedef float f32x4 __attribute__((ext_vector_type(4)));

// LDS-only barrier: does NOT drain vmcnt, so global prefetch loads / fire-and-forget
// stores stay in flight across the barrier (CK block_sync_lds pattern).
__device__ __forceinline__ void sync_lds() {
    asm volatile("s_waitcnt lgkmcnt(0)" ::: "memory");
    __builtin_amdgcn_s_barrier();
}

// ---------------- fused prep: [0,8160) DFT basis | [8160,38400) frames | [38400,39680) WT ----------------
// DFT basis BT[n][j], n<2050: k=n>>1, cos/sin(2*pi*k*(544+j)/2048); v_cos/v_sin take REVOLUTIONS.
__global__ __launch_bounds__(256) void prep_kernel(
    const float* __restrict__ x, const float* __restrict__ w_ih_f, const float* __restrict__ w_ih_b,
    __bf16* __restrict__ BT, __bf16* __restrict__ A, __bf16* __restrict__ WT)
{
    int blk = blockIdx.x;
    if (blk < 8160) {                       // ---- DFT basis
        int id = blk * 256 + threadIdx.x;   // < 2176*960
        int n = id / 960;
        int j = id - n * 960;
        float v = 0.f;
        if (n < 2050) {
            int k = n >> 1;
            int p = (k * (544 + j)) & 2047;             // exact integer phase reduction
            float pr = (float)p * (1.0f / 2048.0f);     // revolutions
            v = (n & 1) ? __builtin_amdgcn_sinf(pr) : __builtin_amdgcn_cosf(pr);
        }
        BT[id] = (__bf16)v;
    } else if (blk < 38400) {               // ---- windowed frames: A[frame][j] = xp[t*240+544+j]*hann960[j]
        int id = (blk - 8160) * 256 + threadIdx.x;      // one thread per 2 cols, < 16128*480
        int frame = id / 480;
        int jp = (id - frame * 480) * 2;
        float v[2] = {0.f, 0.f};
        if (frame < 16016) {
            int b = frame / 1001;
            int t = frame - b * 1001;
            const float* xb = x + (size_t)b * 240000;
            #pragma unroll
            for (int e = 0; e < 2; ++e) {
                int j = jp + e;
                int s = t * 240 + j - 480;              // xp index minus pad
                if (s < 0) s = -s;                      // left reflect
                else if (s >= 240000) s = 479998 - s;   // right reflect (2L-2-s)
                float win = 0.5f - 0.5f * __builtin_amdgcn_cosf((float)j * (1.0f / 960.0f));
                v[e] = xb[s] * win;
            }
        }
        union { unsigned int u; __bf16 h[2]; } pk;
        pk.h[0] = (__bf16)v[0]; pk.h[1] = (__bf16)v[1];
        *reinterpret_cast<unsigned int*>(&A[(size_t)frame * 960 + jp]) = pk.u;
    } else {                                // ---- stacked input-proj weights, transposed + K-padded
        int id = (blk - 38400) * 256 + threadIdx.x;     // < 1024*320
        int n = id / 320;
        int k = id - n * 320;
        float v = 0.f;
        if (k < 301) v = (n < 512) ? w_ih_f[n * 301 + k] : w_ih_b[(n - 512) * 301 + k];
        WT[id] = (__bf16)v;
    }
}

// ---------------- bf16 MFMA GEMM, C = A(M x Ka) * BT(N x Ka)^T.  m97-style staging:
// global_load_lds width=16 into unpadded 128x64 tiles; XOR swizzle chunk^=(row&7) applied
// on the GLOBAL side (LDS dest is wave-uniform base + lane*16) -> fragment ds_read_b128
// is 2-way-per-bank = conflict-free. mode 0: DFT (store bf16 C); mode 1: input projection
// (scatter fp32 into [t][dir][batch][cell][gate] `pre` with bias). ----------------
__global__ __launch_bounds__(256) void gemm_kernel(
    const __bf16* __restrict__ A, const __bf16* __restrict__ BT,
    int Ka, int kIters, int mode,
    __bf16* __restrict__ Cdft, float* __restrict__ pre,
    const float* __restrict__ b_f, const float* __restrict__ b_b)
{
    __shared__ __bf16 As[128 * 64];
    __shared__ __bf16 Bs[128 * 64];
    const int tid = threadIdx.x;
    const int wave = tid >> 6, lane = tid & 63, l15 = lane & 15, quad = lane >> 4;
    const int bn = blockIdx.x, bm = blockIdx.y;
    const int qm = wave >> 1, qn = wave & 1;
    f32x4 acc[4][4] = {};
    const int rl  = lane >> 3;            // row within 8-row chunk
    const int gch = (lane & 7) ^ rl;      // swizzled global 16B-chunk within the 64-col row
    const __bf16* Ag = A + (size_t)(bm * 128) * Ka;
    const __bf16* Bg = BT + (size_t)(bn * 128) * Ka;

    for (int kb = 0; kb < kIters; ++kb) {
        int k0 = kb * 64;
        #pragma unroll
        for (int p = 0; p < 4; ++p) {
            int c = wave + p * 4;          // 16 chunk-instructions cover 128 rows (8 rows each)
            int row = c * 8 + rl;
            __builtin_amdgcn_global_load_lds(
                (const __attribute__((address_space(1))) void*)(Ag + (size_t)row * Ka + k0 + gch * 8),
                (__attribute__((address_space(3))) void*)(As + c * 512), 16, 0, 0);
            __builtin_amdgcn_global_load_lds(
                (const __attribute__((address_space(1))) void*)(Bg + (size_t)row * Ka + k0 + gch * 8),
                (__attribute__((address_space(3))) void*)(Bs + c * 512), 16, 0, 0);
        }
        __syncthreads();
        #pragma unroll
        for (int ks = 0; ks < 2; ++ks) {
            bf16x8 af[4], bfr[4];
            #pragma unroll
            for (int i = 0; i < 4; ++i) {
                int row = qm * 64 + i * 16 + l15;
                int ch = (ks * 4 + quad) ^ (l15 & 7);
                af[i] = *reinterpret_cast<const bf16x8*>(&As[row * 64 + ch * 8]);
            }
            #pragma unroll
            for (int j = 0; j < 4; ++j) {
                int row = qn * 64 + j * 16 + l15;
                int ch = (ks * 4 + quad) ^ (l15 & 7);
                bfr[j] = *reinterpret_cast<const bf16x8*>(&Bs[row * 64 + ch * 8]);
            }
            #pragma unroll
            for (int i = 0; i < 4; ++i)
                #pragma unroll
                for (int j = 0; j < 4; ++j)
                    acc[i][j] = __builtin_amdgcn_mfma_f32_16x16x32_bf16(af[i], bfr[j], acc[i][j], 0, 0, 0);
        }
        __syncthreads();
    }

    if (mode == 0) {
        #pragma unroll
        for (int i = 0; i < 4; ++i)
            #pragma unroll
            for (int j = 0; j < 4; ++j) {
                int n = bn * 128 + qn * 64 + j * 16 + l15;
                #pragma unroll
                for (int r = 0; r < 4; ++r) {
                    int m = bm * 128 + qm * 64 + i * 16 + quad * 4 + r;
                    Cdft[(size_t)m * 2176 + n] = (__bf16)acc[i][j][r];
                }
            }
    } else {
        for (int i = 0; i < 4; ++i)
            for (int j = 0; j < 4; ++j) {
                int n = bn * 128 + qn * 64 + j * 16 + l15;   // n < 1024
                float bias = (n < 512) ? b_f[n] : b_b[n - 512];
                int dirg = n >> 9;
                int ngate = n & 511;
                int g = ngate >> 7;          // gate index: 0=i 1=f 2=g 3=o
                int jj = ngate & 127;        // hidden unit
                for (int r = 0; r < 4; ++r) {
                    int m = bm * 128 + qm * 64 + i * 16 + quad * 4 + r;
                    if (m < 16016) {
                        int b = m / 1001;
                        int t = m - b * 1001;
                        // pre[t][dirg][batch b][cell jj][gate g]
                        size_t off = ((size_t)(t * 2 + dirg) * 16 + b) * 512 + jj * 4 + g;
                        pre[off] = acc[i][j][r] + bias;
                    }
                }
            }
    }
}

// ---------------- feature build: gather harmonic energies from bf16 DFT output ----------------
__global__ __launch_bounds__(320) void build_feat(const float* __restrict__ f0,
    const __bf16* __restrict__ Cdft, __bf16* __restrict__ feat)
{
    int frame = blockIdx.x;
    int d = threadIdx.x;   // 0..319
    float val = 0.f;
    const float LN2 = 0.6931471805599453f;
    {
        int b = frame / 1001;
        int t = frame - b * 1001;
        float f0v = f0[b * 1001 + t];
        float f0nz = (f0v > 0.f) ? f0v : 80.f;   // SR/NUM_BANDS*0.5
        if (d < 300) {
            float mult = (d == 0) ? 0.5f : (float)(d + 1) * 0.5f;
            float harm = f0nz * mult;
            int kidx = (int)rintf(harm * (1.0f / 11.71875f));  // FREQ_INTERVAL = 24000/2048
            kidx = min(max(kidx, 0), 1024);
            float e = 0.f;
            if (kidx < 1024) {   // bin 1024 forced to zero by reference
                unsigned int pk = *reinterpret_cast<const unsigned int*>(&Cdft[(size_t)frame * 2176 + 2 * kidx]);
                union { unsigned int u; __bf16 h[2]; } c; c.u = pk;
                float c0 = (float)c.h[0], c1 = (float)c.h[1];
                e = c0 * c0 + c1 * c1;
            }
            val = (__builtin_amdgcn_logf(e + 1e-8f) * LN2 + 18.f) * (1.f / 23.f);
        } else if (d == 300) {
            val = __builtin_amdgcn_logf(f0nz) * LN2;
        }
    }
    feat[(size_t)frame * 320 + d] = (__bf16)val;
}

// ---------------- batch-parallel BiLSTM: 32 blocks = (batch 16) x (dir 2), one CU each.
// 8 waves; wave w owns perm rows [w*64, w*64+64) of W_hh (perm s=4j+g) in A-register
// fragments -> those rows are EXACTLY cells w*16..w*16+15, all 4 gates. After the MFMAs
// (h broadcast in all 16 B-cols), lane (quad,l15) with quad==(l15&3) holds cell
// w*16+l15's full gate f32x4 in acc[l15>>2]: one 2-level cndmask select, gate chain,
// done — no redundancy, no z LDS round-trip. ONE lgkm-only barrier/step; pre ([t][dir]
// [b][cell][gate], padded +-2 steps) prefetched 2 deep via unroll-2 PA/PB register sets
// (no per-step movs, no vmcnt(0)); h_out stores fire-and-forget. ----------------
__global__ __launch_bounds__(512, 2) void lstm_kernel(
    const float* __restrict__ w_hh_f, const float* __restrict__ w_hh_b,
    const float* __restrict__ pre, float* __restrict__ h_out)
{
    const int bid = blockIdx.x;          // 0..31
    const int b   = bid & 15;
    const int dir = bid >> 4;
    const float* w_hh = dir ? w_hh_b : w_hh_f;
    const int tid = threadIdx.x;
    const int wave = tid >> 6, lane = tid & 63, l15 = lane & 15, quad = lane >> 4;
    const int msel = l15 >> 2;
    const bool own = (quad == (l15 & 3));    // this lane owns cell cellj
    const int cellj = wave * 16 + l15;

    __shared__ __bf16 h_lds[2][128];     // double-buffered h(t)

    // A-fragments: perm row s = wave*64 + mt*16 + l15; W_hh row = (s&3)*128 + (s>>2)
    bf16x8 afrag[4][4];
    #pragma unroll
    for (int mt = 0; mt < 4; ++mt) {
        int s = wave * 64 + mt * 16 + l15;
        const float* wrow = w_hh + (size_t)((s & 3) * 128 + (s >> 2)) * 128;
        #pragma unroll
        for (int kt = 0; kt < 4; ++kt) {
            bf16x8 v;
            #pragma unroll
            for (int e = 0; e < 8; ++e) v[e] = (__bf16)wrow[kt * 32 + quad * 8 + e];
            afrag[mt][kt] = v;
        }
    }

    if (tid < 128) h_lds[0][tid] = (__bf16)0.f;

    const int t0 = dir ? 1000 : 0;
    const ptrdiff_t pre_sstride  = dir ? -16384 : 16384;   // floats per step
    const ptrdiff_t hout_sstride = dir ? -2048  : 2048;    // floats per step
    // pre[t][dir][b][cell][gate]; this lane reads cell cellj's 4 gates
    const float* pre_base = pre + ((size_t)(t0 * 2 + dir) * 16 + b) * 512 + (size_t)cellj * 4;
    float* hout_base = h_out + (((size_t)dir * 1001 + t0) * 16 + b) * 128;

    float cstate = 0.f;
    const float L2E = 1.4426950408889634f;

    auto body = [&](int s, f32x4 P) {
        const __bf16* hb = h_lds[s & 1];
        bf16x8 bfr[4];
        #pragma unroll
        for (int kt = 0; kt < 4; ++kt)
            bfr[kt] = *reinterpret_cast<const bf16x8*>(&hb[kt * 32 + quad * 8]);

        f32x4 acc[4] = {};
        #pragma unroll
        for (int kt = 0; kt < 4; ++kt)
            #pragma unroll
            for (int mt = 0; mt < 4; ++mt)
                acc[mt] = __builtin_amdgcn_mfma_f32_16x16x32_bf16(afrag[mt][kt], bfr[kt], acc[mt], 0, 0, 0);

        // z4 = acc[msel] (valid on lanes with quad == (l15&3))
        f32x4 t01 = (msel & 1) ? acc[1] : acc[0];
        f32x4 t23 = (msel & 1) ? acc[3] : acc[2];
        f32x4 z4  = (msel & 2) ? t23 : t01;

        float zi = z4[0] + P[0], zf = z4[1] + P[1];
        float zg = z4[2] + P[2], zo = z4[3] + P[3];
        // fused gates: 5 exp2 + 3 rcp, exact algebra
        float A = __builtin_amdgcn_exp2f(-L2E * zi);
        float B = __builtin_amdgcn_exp2f(-L2E * zf);
        float C = __builtin_amdgcn_exp2f(-2.f * L2E * zg);
        float D = __builtin_amdgcn_exp2f(-L2E * zo);
        float Pp = (1.f + A) * (1.f + C);
        float Q = 1.f + B;
        float cn = (cstate * Pp + (1.f - C) * Q) * __builtin_amdgcn_rcpf(Pp * Q);
        if (own) cstate = cn;
        float E = __builtin_amdgcn_exp2f(-2.f * L2E * cn);
        float h = (1.f - E) * __builtin_amdgcn_rcpf((1.f + D) * (1.f + E));

        if (own) {
            h_lds[(s + 1) & 1][cellj] = (__bf16)h;
            hout_base[(ptrdiff_t)s * hout_sstride + cellj] = h;   // fire-and-forget
        }
    };

    auto load_pre = [&](int sidx) -> f32x4 {
        return *reinterpret_cast<const f32x4*>(pre_base + (ptrdiff_t)sidx * pre_sstride);
    };

    f32x4 PA = load_pre(0);
    f32x4 PB = load_pre(1);
    __syncthreads();   // h_lds[0] init visible

    for (int s = 0; s < 1001; s += 2) {
        body(s, PA);
        PA = load_pre(s + 2);   // unconditional: pre is padded +-2 steps
        sync_lds();
        if (s + 1 < 1001) {
            body(s + 1, PB);
            PB = load_pre(s + 3);
            sync_lds();
        }
    }
}

// ---------------- LayerNorm(concat(hf,hb)) + out projection; one wave per (b,t) row ----------------
__global__ __launch_bounds__(256) void out_kernel(
    const float* __restrict__ h_out, const float* __restrict__ ln_g, const float* __restrict__ ln_b,
    const float* __restrict__ out_w, const float* __restrict__ out_b, float* __restrict__ out)
{
    __shared__ __bf16 w_lds[256 * 66];   // [k][o], padded: conflict-free both directions
    __shared__ float hn_lds[4 * 256];
    const int tid = threadIdx.x;
    const int wave = tid >> 6, lane = tid & 63;
    for (int idx = tid; idx < 16384; idx += 256) {
        int o = idx >> 8, k = idx & 255;
        w_lds[k * 66 + o] = (__bf16)out_w[o * 256 + k];
    }
    int r = blockIdx.x * 4 + wave;       // < 16016
    int b = r / 1001, t = r - b * 1001;
    size_t basef = (((size_t)0 * 1001 + t) * 16 + b) * 128;
    size_t baseb = (((size_t)1 * 1001 + t) * 16 + b) * 128;
    float h0 = h_out[basef + lane];
    float h1 = h_out[basef + 64 + lane];
    float h2 = h_out[baseb + lane];
    float h3 = h_out[baseb + 64 + lane];
    float s1 = h0 + h1 + h2 + h3;
    float s2 = h0 * h0 + h1 * h1 + h2 * h2 + h3 * h3;
    #pragma unroll
    for (int m = 32; m >= 1; m >>= 1) {
        s1 += __shfl_xor(s1, m, 64);
        s2 += __shfl_xor(s2, m, 64);
    }
    float mu = s1 * (1.f / 256.f);
    float var = s2 * (1.f / 256.f) - mu * mu;   // biased var, matches jnp var
    float rstd = rsqrtf(var + 1e-5f);
    int k0 = lane, k1 = 64 + lane, k2 = 128 + lane, k3 = 192 + lane;
    hn_lds[wave * 256 + k0] = (h0 - mu) * rstd * ln_g[k0] + ln_b[k0];
    hn_lds[wave * 256 + k1] = (h1 - mu) * rstd * ln_g[k1] + ln_b[k1];
    hn_lds[wave * 256 + k2] = (h2 - mu) * rstd * ln_g[k2] + ln_b[k2];
    hn_lds[wave * 256 + k3] = (h3 - mu) * rstd * ln_g[k3] + ln_b[k3];
    __syncthreads();
    const float* hn = &hn_lds[wave * 256];
    float acc = 0.f;
    #pragma unroll 4
    for (int k = 0; k < 256; ++k)
        acc += hn[k] * (float)w_lds[k * 66 + lane];   // hn[k]: LDS broadcast
    out[(size_t)r * 64 + lane] = acc + out_b[lane];
}

extern "C" void kernel_launch(void* const* d_in, const int* in_sizes, int n_in,
                              void* d_out, int out_size, void* d_ws, size_t ws_size,
                              hipStream_t stream) {
    const float* x      = (const float*)d_in[0];
    const float* f0     = (const float*)d_in[1];
    const float* w_ih_f = (const float*)d_in[2];
    const float* w_hh_f = (const float*)d_in[3];
    const float* b_f    = (const float*)d_in[4];
    const float* w_ih_b = (const float*)d_in[5];
    const float* w_hh_b = (const float*)d_in[6];
    const float* b_b    = (const float*)d_in[7];
    const float* ln_g   = (const float*)d_in[8];
    const float* ln_b   = (const float*)d_in[9];
    const float* out_w  = (const float*)d_in[10];
    const float* out_b  = (const float*)d_in[11];
    float* out = (float*)d_out;

    char* ws = (char*)d_ws;
    size_t off = 0;
    auto alloc = [&](size_t bytes) { size_t o = off; off = (off + bytes + 255) & ~(size_t)255; return o; };
    __bf16* A     = (__bf16*)(ws + alloc((size_t)16128 * 960 * 2));
    __bf16* BT    = (__bf16*)(ws + alloc((size_t)2176 * 960 * 2));
    __bf16* Cdft  = (__bf16*)(ws + alloc((size_t)16128 * 2176 * 2));
    __bf16* feat  = (__bf16*)(ws + alloc((size_t)16128 * 320 * 2));
    __bf16* WT    = (__bf16*)(ws + alloc((size_t)1024 * 320 * 2));
    // pre padded +-2 timesteps so the LSTM prefetch needs no bounds check
    float*  preA  = (float*)(ws + alloc((size_t)(1001 * 2 + 8) * 16 * 512 * 4));
    float*  pre   = preA + (size_t)4 * 16 * 512;
    float*  h_out = (float*)(ws + alloc((size_t)2 * 1001 * 16 * 128 * 4));
    (void)ws_size; (void)in_sizes; (void)n_in; (void)out_size;

    prep_kernel <<<39680, 256, 0, stream>>>(x, w_ih_f, w_ih_b, BT, A, WT);
    gemm_kernel <<<dim3(17, 126), 256, 0, stream>>>(A, BT, 960, 15, 0, Cdft, nullptr, nullptr, nullptr);
    build_feat  <<<16016, 320, 0, stream>>>(f0, Cdft, feat);
    gemm_kernel <<<dim3(8, 126), 256, 0, stream>>>(feat, WT, 320, 5, 1, nullptr, pre, b_f, b_b);
    lstm_kernel <<<32, 512, 0, stream>>>(w_hh_f, w_hh_b, pre, h_out);
    out_kernel  <<<4004, 256, 0, stream>>>(h_out, ln_g, ln_b, out_w, out_b, out);
}